// Round 1
// baseline (382.646 us; speedup 1.0000x reference)
//
#include <hip/hip_runtime.h>
#include <hip/hip_bf16.h>
#include <stdint.h>

#define RANK 32
#define SCALE (1.0f / 32.0f)

#define BM 128
#define BN 128
#define BK 32

typedef __bf16 bf16x8 __attribute__((ext_vector_type(8)));
typedef float f32x4 __attribute__((ext_vector_type(4)));

// ---------------------------------------------------------------------------
// async global->LDS, 16B per lane (HipKittens-style addrspace casts)
// ---------------------------------------------------------------------------
__device__ __forceinline__ void gload16(const void* g, void* l) {
  __builtin_amdgcn_global_load_lds(
      (const __attribute__((address_space(1))) unsigned int*)g,
      (__attribute__((address_space(3))) unsigned int*)l, 16, 0, 0);
}

__device__ __forceinline__ unsigned short f2bf(float f) {
  __hip_bfloat16 h = __float2bfloat16(f);
  return *reinterpret_cast<unsigned short*>(&h);
}

// ---------------------------------------------------------------------------
// Bt[o][r] = B[r][o]   (so merge_W reads both rank vectors contiguously)
// ---------------------------------------------------------------------------
__global__ __launch_bounds__(256) void transpose_B_k(const float* __restrict__ B,
                                                     float* __restrict__ Bt,
                                                     int Dout) {
  int idx = blockIdx.x * 256 + threadIdx.x;  // r*Dout + o, coalesced read
  int r = idx / Dout;
  int o = idx - r * Dout;
  Bt[(long long)o * RANK + r] = B[idx];
}

// ---------------------------------------------------------------------------
// W'b[o][i] = bf16( W[o][i] + SCALE * dot32(A[i][:], Bt[o][:]) )
// tile: 16 o-rows x 256 i-cols per block
// ---------------------------------------------------------------------------
__global__ __launch_bounds__(256) void merge_W_k(const float* __restrict__ W,
                                                 const float* __restrict__ A,
                                                 const float* __restrict__ Bt,
                                                 unsigned short* __restrict__ Wb,
                                                 int Din, int Dout) {
  __shared__ float sB[16 * RANK];
  int nib = Din / 256;
  int ib = blockIdx.x % nib;
  int ob = blockIdx.x / nib;
  int i0 = ib * 256, o0 = ob * 16;
  int t = threadIdx.x;

  if (t < 128) {
    reinterpret_cast<float4*>(sB)[t] =
        reinterpret_cast<const float4*>(Bt + (long long)o0 * RANK)[t];
  }

  float a[RANK];
  const float4* Ap = reinterpret_cast<const float4*>(A + (long long)(i0 + t) * RANK);
#pragma unroll
  for (int c = 0; c < RANK / 4; ++c) {
    float4 v = Ap[c];
    a[c * 4 + 0] = v.x; a[c * 4 + 1] = v.y;
    a[c * 4 + 2] = v.z; a[c * 4 + 3] = v.w;
  }
  __syncthreads();

  for (int o = 0; o < 16; ++o) {
    float d = 0.f;
#pragma unroll
    for (int j = 0; j < RANK; ++j) d += a[j] * sB[o * RANK + j];  // sB broadcast
    long long off = (long long)(o0 + o) * Din + i0 + t;
    Wb[off] = f2bf(W[off] + SCALE * d);
  }
}

// ---------------------------------------------------------------------------
// x fp32 -> bf16, 8 elements / thread, 16B stores
// ---------------------------------------------------------------------------
__global__ __launch_bounds__(256) void cast_x_k(const float* __restrict__ in,
                                                unsigned short* __restrict__ out,
                                                long long n8) {
  long long i = (long long)blockIdx.x * 256 + threadIdx.x;
  if (i >= n8) return;
  const float4* in4 = reinterpret_cast<const float4*>(in) + i * 2;
  float4 v0 = in4[0], v1 = in4[1];
  union { unsigned short u[8]; uint4 q; } p;
  p.u[0] = f2bf(v0.x); p.u[1] = f2bf(v0.y); p.u[2] = f2bf(v0.z); p.u[3] = f2bf(v0.w);
  p.u[4] = f2bf(v1.x); p.u[5] = f2bf(v1.y); p.u[6] = f2bf(v1.z); p.u[7] = f2bf(v1.w);
  reinterpret_cast<uint4*>(out)[i] = p.q;
}

// ---------------------------------------------------------------------------
// out[m][n] = sum_k Xb[m][k]*Wb[n][k] + bias[n]     (m97 structure: 128x128,
// BK=32, 4 waves in 2x2, 4x4 16x16x32 frags/wave, global_load_lds width=16)
// ---------------------------------------------------------------------------
__global__ __launch_bounds__(256, 2) void gemm_bt_bias_k(
    const unsigned short* __restrict__ Xb,   // [M][K] bf16
    const unsigned short* __restrict__ Wb,   // [N][K] bf16
    const float* __restrict__ bias,          // [N]
    float* __restrict__ Out,                 // [M][N] fp32
    int M, int N, int K) {
  __shared__ unsigned short As[BM * BK];
  __shared__ unsigned short Bs[BN * BK];

  int nbn = N / BN;
  int bm = blockIdx.x / nbn;
  int bn = blockIdx.x % nbn;
  int tid = threadIdx.x;
  int wid = tid >> 6;
  int lane = tid & 63;
  int wr = wid >> 1, wc = wid & 1;

  const unsigned short* ga = Xb + (long long)bm * BM * K;
  const unsigned short* gb = Wb + (long long)bn * BN * K;
  int rlo = lane >> 2;        // 0..15 row within 16-row wave chunk
  int col = (lane & 3) * 8;   // 0,8,16,24

  f32x4 acc[4][4] = {};

  for (int kt = 0; kt < K; kt += BK) {
    // stage A,B tiles: per wave 16 rows x 32 cols = 1024B per issue (lane*16B linear)
    gload16(ga + (long long)(wid * 16 + rlo) * K + kt + col, &As[wid * 512]);
    gload16(ga + (long long)(64 + wid * 16 + rlo) * K + kt + col, &As[(4 + wid) * 512]);
    gload16(gb + (long long)(wid * 16 + rlo) * K + kt + col, &Bs[wid * 512]);
    gload16(gb + (long long)(64 + wid * 16 + rlo) * K + kt + col, &Bs[(4 + wid) * 512]);
    __syncthreads();  // compiler drains vmcnt(0) before s_barrier

    int arow = wr * 64 + (lane & 15);
    int brow = wc * 64 + (lane & 15);
    int koff = (lane >> 4) * 8;
    bf16x8 af[4], bfr[4];
#pragma unroll
    for (int i = 0; i < 4; ++i)
      af[i] = *reinterpret_cast<const bf16x8*>(&As[(arow + i * 16) * BK + koff]);
#pragma unroll
    for (int j = 0; j < 4; ++j)
      bfr[j] = *reinterpret_cast<const bf16x8*>(&Bs[(brow + j * 16) * BK + koff]);
#pragma unroll
    for (int i = 0; i < 4; ++i)
#pragma unroll
      for (int j = 0; j < 4; ++j)
        acc[i][j] = __builtin_amdgcn_mfma_f32_16x16x32_bf16(af[i], bfr[j], acc[i][j], 0, 0, 0);
    __syncthreads();
  }

  // epilogue: C/D layout col=lane&15, row=(lane>>4)*4+v  [m89/m91 verified]
  int orow = bm * BM + wr * 64;
  int ocol = bn * BN + wc * 64;
#pragma unroll
  for (int j = 0; j < 4; ++j) {
    int gc = ocol + j * 16 + (lane & 15);
    float bv = bias[gc];
#pragma unroll
    for (int i = 0; i < 4; ++i) {
      int gr = orow + i * 16 + (lane >> 4) * 4;
#pragma unroll
      for (int v = 0; v < 4; ++v)
        Out[(long long)(gr + v) * N + gc] = acc[i][j][v] + bv;
    }
  }
}

// ---------------------------------------------------------------------------
extern "C" void kernel_launch(void* const* d_in, const int* in_sizes, int n_in,
                              void* d_out, int out_size, void* d_ws, size_t ws_size,
                              hipStream_t stream) {
  const float* x    = (const float*)d_in[0];
  const float* W    = (const float*)d_in[1];
  const float* bias = (const float*)d_in[2];
  const float* A    = (const float*)d_in[3];
  const float* B    = (const float*)d_in[4];

  int Din  = in_sizes[3] / RANK;                 // 4096
  int Dout = in_sizes[4] / RANK;                 // 4096
  long long M = (long long)in_sizes[0] / Din;    // 8192

  size_t xb_bytes = (size_t)M * Din * 2;
  size_t wb_bytes = (size_t)Dout * Din * 2;
  size_t bt_bytes = (size_t)Dout * RANK * 4;
  if (ws_size < xb_bytes + wb_bytes + bt_bytes) return;  // fail loudly

  char* ws = (char*)d_ws;
  unsigned short* Xb = (unsigned short*)ws;
  unsigned short* Wb = (unsigned short*)(ws + xb_bytes);
  float* Bt          = (float*)(ws + xb_bytes + wb_bytes);

  transpose_B_k<<<dim3((Dout * RANK) / 256), dim3(256), 0, stream>>>(B, Bt, Dout);
  merge_W_k<<<dim3((Dout / 16) * (Din / 256)), dim3(256), 0, stream>>>(W, A, Bt, Wb, Din, Dout);
  long long n8 = M * Din / 8;
  cast_x_k<<<dim3((unsigned)(n8 / 256)), dim3(256), 0, stream>>>(x, Xb, n8);
  gemm_bt_bias_k<<<dim3((unsigned)((M / BM) * (Dout / BN))), dim3(256), 0, stream>>>(
      Xb, Wb, bias, (float*)d_out, (int)M, Dout, Din);
}

// Round 2
// 362.536 us; speedup vs baseline: 1.0555x; 1.0555x over previous
//
#include <hip/hip_runtime.h>
#include <hip/hip_bf16.h>
#include <stdint.h>

#define RANK 32
#define SCALE (1.0f / 32.0f)

typedef __bf16 bf16x8 __attribute__((ext_vector_type(8)));
typedef float f32x4 __attribute__((ext_vector_type(4)));

// ---------------------------------------------------------------------------
// async global->LDS, 16B per lane
// ---------------------------------------------------------------------------
__device__ __forceinline__ void gload16(const void* g, void* l) {
  __builtin_amdgcn_global_load_lds(
      (const __attribute__((address_space(1))) unsigned int*)g,
      (__attribute__((address_space(3))) unsigned int*)l, 16, 0, 0);
}

__device__ __forceinline__ unsigned short f2bf(float f) {
  __hip_bfloat16 h = __float2bfloat16(f);
  return *reinterpret_cast<unsigned short*>(&h);
}

// ---------------------------------------------------------------------------
// Bt[o][r] = B[r][o]
// ---------------------------------------------------------------------------
__global__ __launch_bounds__(256) void transpose_B_k(const float* __restrict__ B,
                                                     float* __restrict__ Bt,
                                                     int Dout) {
  int idx = blockIdx.x * 256 + threadIdx.x;
  int r = idx / Dout;
  int o = idx - r * Dout;
  Bt[(long long)o * RANK + r] = B[idx];
}

// ---------------------------------------------------------------------------
// W'b[o][i] = bf16( W[o][i] + SCALE * dot32(A[i][:], Bt[o][:]) )
// ---------------------------------------------------------------------------
__global__ __launch_bounds__(256) void merge_W_k(const float* __restrict__ W,
                                                 const float* __restrict__ A,
                                                 const float* __restrict__ Bt,
                                                 unsigned short* __restrict__ Wb,
                                                 int Din, int Dout) {
  __shared__ float sB[16 * RANK];
  int nib = Din / 256;
  int ib = blockIdx.x % nib;
  int ob = blockIdx.x / nib;
  int i0 = ib * 256, o0 = ob * 16;
  int t = threadIdx.x;

  if (t < 128) {
    reinterpret_cast<float4*>(sB)[t] =
        reinterpret_cast<const float4*>(Bt + (long long)o0 * RANK)[t];
  }

  float a[RANK];
  const float4* Ap = reinterpret_cast<const float4*>(A + (long long)(i0 + t) * RANK);
#pragma unroll
  for (int c = 0; c < RANK / 4; ++c) {
    float4 v = Ap[c];
    a[c * 4 + 0] = v.x; a[c * 4 + 1] = v.y;
    a[c * 4 + 2] = v.z; a[c * 4 + 3] = v.w;
  }
  __syncthreads();

  for (int o = 0; o < 16; ++o) {
    float d = 0.f;
#pragma unroll
    for (int j = 0; j < RANK; ++j) d += a[j] * sB[o * RANK + j];
    long long off = (long long)(o0 + o) * Din + i0 + t;
    Wb[off] = f2bf(W[off] + SCALE * d);
  }
}

// ---------------------------------------------------------------------------
// x fp32 -> bf16, 8 elems/thread
// ---------------------------------------------------------------------------
__global__ __launch_bounds__(256) void cast_x_k(const float* __restrict__ in,
                                                unsigned short* __restrict__ out,
                                                long long n8) {
  long long i = (long long)blockIdx.x * 256 + threadIdx.x;
  if (i >= n8) return;
  const float4* in4 = reinterpret_cast<const float4*>(in) + i * 2;
  float4 v0 = in4[0], v1 = in4[1];
  union { unsigned short u[8]; uint4 q; } p;
  p.u[0] = f2bf(v0.x); p.u[1] = f2bf(v0.y); p.u[2] = f2bf(v0.z); p.u[3] = f2bf(v0.w);
  p.u[4] = f2bf(v1.x); p.u[5] = f2bf(v1.y); p.u[6] = f2bf(v1.z); p.u[7] = f2bf(v1.w);
  reinterpret_cast<uint4*>(out)[i] = p.q;
}

// ---------------------------------------------------------------------------
// 256x256 / BK=64 / 8-wave (2x4) / 8-phase counted-vmcnt GEMM (m201 template)
// out[m][n] = sum_k Xb[m][k]*Wb[n][k] + bias[n]
//
// LDS: As/Bs [2][256][64] bf16 = 128 KiB. Staged via global_load_lds width=16
// with INVERSE-swizzled global source; ds_read applies the matching XOR
// (chunk ^= row&7, 16B chunks within a 128B row) -> conflict-free b128 reads.
//
// Stage schedule (one vmcnt(4) per K-tile, never 0 in steady state):
//   X.p1: B(X+1) rows 0-127   -> buf[cur^1]   (2 gloads)
//   X.p2: B(X+1) rows 128-255 -> buf[cur^1]   (2 gloads)
//   X.p4: A(X+2) all          -> buf[cur]     (4 gloads), then vmcnt(4)
// Guarantee: vmcnt(4) at X.p4 leaves only A(X+2) outstanding => all of tile
// X+1 (A staged at (X-1).p4, B at X.p1/p2) complete before (X+1).p1.
// Buffer safety: A(X+2) overwrites buf[cur] A-region, last ds_read at X.p3
// (barrier-separated); B(X+1) goes to the opposite buffer, idle since
// (X-1).p2.
// ---------------------------------------------------------------------------
template <int NISSUE>
__device__ __forceinline__ void stage(const unsigned short* g, int K, int koff,
                                      int row0, unsigned short* ldsbase,
                                      int t, int wid) {
  int r = t >> 3;                    // local row within 64-row issue
  int cg = (t & 7) ^ (r & 7);        // inverse-swizzled global 16B chunk
#pragma unroll
  for (int i = 0; i < NISSUE; ++i) {
    gload16(g + (long long)(row0 + i * 64 + r) * K + koff + cg * 8,
            ldsbase + (row0 + i * 64) * 64 + wid * 512);
  }
}

__device__ __forceinline__ int swz_off(int rowl, int k) {
  // element offset of (rowl, k..k+7) under st-swizzle (16B chunk XOR row&7)
  return rowl * 64 + ((((k) >> 3) ^ (rowl & 7)) << 3);
}

__global__ __launch_bounds__(512, 2) void gemm256_bias_k(
    const unsigned short* __restrict__ Xb,   // [M][K] bf16
    const unsigned short* __restrict__ Wb,   // [N][K] bf16
    const float* __restrict__ bias,          // [N]
    float* __restrict__ Out,                 // [M][N] fp32
    int M, int N, int K) {
  __shared__ unsigned short As[2][256 * 64];
  __shared__ unsigned short Bs[2][256 * 64];

  int nbn = N / 256;
  int cpx = gridDim.x >> 3;                    // grid % 8 == 0
  int bid = blockIdx.x;
  int swz = (bid & 7) * cpx + (bid >> 3);      // XCD-aware swizzle (T1)
  int bm = swz / nbn, bn = swz % nbn;

  int t = threadIdx.x;
  int wid = t >> 6, lane = t & 63;
  int wr = wid >> 2, wc = wid & 3;             // 2x4 wave grid
  int lr = lane & 15, kq = (lane >> 4) * 8;
  int aw = wr * 128, bw = wc * 64;

  const unsigned short* ga = Xb + (long long)bm * 256 * K;
  const unsigned short* gb = Wb + (long long)bn * 256 * K;

  f32x4 acc[8][4] = {};
  bf16x8 a[4][2], b0[2][2], b1[2][2];

  const int NT = K / 64;

  // prologue: A(T0), B(T0), A(T1); keep A(T1) in flight
  stage<4>(ga, K, 0, 0, As[0], t, wid);
  stage<4>(gb, K, 0, 0, Bs[0], t, wid);
  stage<4>(ga, K, 64, 0, As[1], t, wid);
  asm volatile("s_waitcnt vmcnt(4)" ::: "memory");
  __builtin_amdgcn_s_barrier();

  for (int kt = 0; kt < NT; ++kt) {
    int cur = kt & 1;
    const unsigned short* Ac = As[cur];
    const unsigned short* Bc = Bs[cur];
    unsigned short* An = As[cur];        // A(kt+2) reuses current A buffer
    unsigned short* Bn = Bs[cur ^ 1];
    int konext = (kt + 1) * 64, konext2 = (kt + 2) * 64;

    // ---------- phase 1: read A-lo + B-lo; stage B(next) rows 0-127
#pragma unroll
    for (int m = 0; m < 4; ++m)
#pragma unroll
      for (int ks = 0; ks < 2; ++ks)
        a[m][ks] = *(const bf16x8*)&Ac[swz_off(aw + m * 16 + lr, ks * 32 + kq)];
#pragma unroll
    for (int n = 0; n < 2; ++n)
#pragma unroll
      for (int ks = 0; ks < 2; ++ks)
        b0[n][ks] = *(const bf16x8*)&Bc[swz_off(bw + n * 16 + lr, ks * 32 + kq)];
    if (kt + 1 < NT) stage<2>(gb, K, konext, 0, Bn, t, wid);
    __builtin_amdgcn_s_barrier();
    asm volatile("s_waitcnt lgkmcnt(0)" ::: "memory");
    __builtin_amdgcn_s_setprio(1);
#pragma unroll
    for (int m = 0; m < 4; ++m)
#pragma unroll
      for (int n = 0; n < 2; ++n)
#pragma unroll
        for (int ks = 0; ks < 2; ++ks)
          acc[m][n] = __builtin_amdgcn_mfma_f32_16x16x32_bf16(a[m][ks], b0[n][ks], acc[m][n], 0, 0, 0);
    __builtin_amdgcn_s_setprio(0);
    __builtin_amdgcn_s_barrier();

    // ---------- phase 2: read B-hi; stage B(next) rows 128-255
#pragma unroll
    for (int n = 0; n < 2; ++n)
#pragma unroll
      for (int ks = 0; ks < 2; ++ks)
        b1[n][ks] = *(const bf16x8*)&Bc[swz_off(bw + 32 + n * 16 + lr, ks * 32 + kq)];
    if (kt + 1 < NT) stage<2>(gb, K, konext, 128, Bn, t, wid);
    __builtin_amdgcn_s_barrier();
    asm volatile("s_waitcnt lgkmcnt(0)" ::: "memory");
    __builtin_amdgcn_s_setprio(1);
#pragma unroll
    for (int m = 0; m < 4; ++m)
#pragma unroll
      for (int n = 0; n < 2; ++n)
#pragma unroll
        for (int ks = 0; ks < 2; ++ks)
          acc[m][2 + n] = __builtin_amdgcn_mfma_f32_16x16x32_bf16(a[m][ks], b1[n][ks], acc[m][2 + n], 0, 0, 0);
    __builtin_amdgcn_s_setprio(0);
    __builtin_amdgcn_s_barrier();

    // ---------- phase 3: read A-hi (overwrites a[][]); no stage
#pragma unroll
    for (int m = 0; m < 4; ++m)
#pragma unroll
      for (int ks = 0; ks < 2; ++ks)
        a[m][ks] = *(const bf16x8*)&Ac[swz_off(aw + 64 + m * 16 + lr, ks * 32 + kq)];
    __builtin_amdgcn_s_barrier();
    asm volatile("s_waitcnt lgkmcnt(0)" ::: "memory");
    __builtin_amdgcn_s_setprio(1);
#pragma unroll
    for (int m = 0; m < 4; ++m)
#pragma unroll
      for (int n = 0; n < 2; ++n)
#pragma unroll
        for (int ks = 0; ks < 2; ++ks)
          acc[4 + m][2 + n] = __builtin_amdgcn_mfma_f32_16x16x32_bf16(a[m][ks], b1[n][ks], acc[4 + m][2 + n], 0, 0, 0);
    __builtin_amdgcn_s_setprio(0);
    __builtin_amdgcn_s_barrier();

    // ---------- phase 4: stage A(kt+2); counted vmcnt; Q10
    if (kt + 2 < NT) {
      stage<4>(ga, K, konext2, 0, An, t, wid);
      asm volatile("s_waitcnt vmcnt(4)" ::: "memory");
    } else if (kt + 1 < NT) {
      asm volatile("s_waitcnt vmcnt(0)" ::: "memory");
    }
    __builtin_amdgcn_s_barrier();
    __builtin_amdgcn_s_setprio(1);
#pragma unroll
    for (int m = 0; m < 4; ++m)
#pragma unroll
      for (int n = 0; n < 2; ++n)
#pragma unroll
        for (int ks = 0; ks < 2; ++ks)
          acc[4 + m][n] = __builtin_amdgcn_mfma_f32_16x16x32_bf16(a[m][ks], b0[n][ks], acc[4 + m][n], 0, 0, 0);
    __builtin_amdgcn_s_setprio(0);
    __builtin_amdgcn_s_barrier();
  }

  // epilogue: C/D layout col=lane&15, row=(lane>>4)*4+v
  long long orow = (long long)bm * 256 + wr * 128;
  int ocol = bn * 256 + wc * 64;
#pragma unroll
  for (int n = 0; n < 4; ++n) {
    int gc = ocol + n * 16 + lr;
    float bv = bias[gc];
#pragma unroll
    for (int m = 0; m < 8; ++m) {
      long long gr = orow + m * 16 + (lane >> 4) * 4;
#pragma unroll
      for (int v = 0; v < 4; ++v)
        Out[(gr + v) * N + gc] = acc[m][n][v] + bv;
    }
  }
}

// ---------------------------------------------------------------------------
extern "C" void kernel_launch(void* const* d_in, const int* in_sizes, int n_in,
                              void* d_out, int out_size, void* d_ws, size_t ws_size,
                              hipStream_t stream) {
  const float* x    = (const float*)d_in[0];
  const float* W    = (const float*)d_in[1];
  const float* bias = (const float*)d_in[2];
  const float* A    = (const float*)d_in[3];
  const float* B    = (const float*)d_in[4];

  int Din  = in_sizes[3] / RANK;                 // 4096
  int Dout = in_sizes[4] / RANK;                 // 4096
  long long M = (long long)in_sizes[0] / Din;    // 8192

  size_t xb_bytes = (size_t)M * Din * 2;
  size_t wb_bytes = (size_t)Dout * Din * 2;
  size_t bt_bytes = (size_t)Dout * RANK * 4;
  if (ws_size < xb_bytes + wb_bytes + bt_bytes) return;

  char* ws = (char*)d_ws;
  unsigned short* Xb = (unsigned short*)ws;
  unsigned short* Wb = (unsigned short*)(ws + xb_bytes);
  float* Bt          = (float*)(ws + xb_bytes + wb_bytes);

  transpose_B_k<<<dim3((Dout * RANK) / 256), dim3(256), 0, stream>>>(B, Bt, Dout);
  merge_W_k<<<dim3((Dout / 16) * (Din / 256)), dim3(256), 0, stream>>>(W, A, Bt, Wb, Din, Dout);
  long long n8 = M * Din / 8;
  cast_x_k<<<dim3((unsigned)(n8 / 256)), dim3(256), 0, stream>>>(x, Xb, n8);
  gemm256_bias_k<<<dim3((unsigned)((M / 256) * (Dout / 256))), dim3(512), 0, stream>>>(
      Xb, Wb, bias, (float*)d_out, (int)M, Dout, Din);
}